// Round 1
// 90.718 us; speedup vs baseline: 1.0068x; 1.0068x over previous
//
#include <hip/hip_runtime.h>
#include <stdint.h>

#define NQ 12
#define DIM 4096
#define NLAYERS 6
#define TPB 512

typedef float v2f __attribute__((ext_vector_type(2)));

// ---------------------------------------------------------------------------
// R13: occupancy push. 512 threads/block (was 256) => 8 waves/block, 2
// blocks/CU => 4 waves/SIMD (was 2). Per-thread state halves to 8 complex:
//   k bits: 0-1 local (j), 2 pack (v2f lane), 3-8 lane (tid 0-5),
//           9-11 wave (tid 6-8).
// Window = 3 wires => 4 windows/layer, 23 passes total, but the two extra
// passes are wave-local (lgkmcnt only); cross-wave barriers/layer unchanged.
//   Layer l: [P_c = rebase: fold CNOT A_{l-1}, cross-wave, 1 barrier]
//            gates w11,w10 + pack w9
//            P1: swap {0-2}<->{3-5}   (wave-local)
//            gates w8,w7 + pack w6
//            P2: swap {0-2}<->{6-8}   (wave-local)
//            gates w5,w4 + pack w3
//            P3: swap {0-2}<->{9-11}  (cross-wave, pre+post barrier)
//            gates w2,w1 + pack w0
//   Basis algebra (data_new[k] = data_old[M(k)]):
//     Phi = S1.S2.S3 ; M_c = Phi^-1.A = S3.S2.S1.A
//     (columns: S3f(S2f(S1f(Acols)))); epilogue i(k) = A5^-1(S1f(S2f(S3f(k)))).
//   All passes: 8 b64 writes + 16 b32 scatter reads per thread. Layouts:
//   row0 = pack functional (b64-pair writes), rows 1-4 greedy rank-4 on
//   write/read lane spans (same builder, bit positions shifted).
// ---------------------------------------------------------------------------
struct Pass_t {
    uint32_t WT[9];    // Lambda cols, k bits 3..11
    uint32_t WL[4];    // Lambda(j), local bits 0..1
    uint32_t RT[9];    // (Lambda o M) cols, k bits 3..11
    uint32_t RL[8];    // (Lambda o M)(l), local bits 0..2 (bit2 = pack)
};
struct Pass9_t {       // wave-local: 9-bit space (k bits 0..8)
    uint32_t WT[6];
    uint32_t WL[4];
    uint32_t RT[6];
    uint32_t RL[8];
};
struct CK_t {
    Pass9_t PA1;           // swap {0-2}<->{3-5}, wave-local
    Pass9_t PA2;           // swap {0-2}<->{6-8}, wave-local
    Pass_t PB;             // swap {0-2}<->{9-11}, cross-wave
    Pass_t P1[NLAYERS];    // rebase (index 1..5 used)
    uint32_t frow[NQ];     // epilogue sign rows
};

constexpr uint32_t S1f(uint32_t k){ return (k & 0xFC0u) | ((k & 7u) << 3) | ((k >> 3) & 7u); }
constexpr uint32_t S2f(uint32_t k){ return (k & 0xE38u) | ((k & 7u) << 6) | ((k >> 6) & 7u); }
constexpr uint32_t S3f(uint32_t k){ return (k & 0x1F8u) | ((k & 7u) << 9) | ((k >> 9) & 7u); }

constexpr uint32_t ech_reduce(const uint32_t* v, int n, uint32_t x){
    bool ch = true;
    while (ch) {
        ch = false;
        for (int i = 0; i < n; i++)
            if (v[i] && (x ^ v[i]) < x) { x ^= v[i]; ch = true; }
    }
    return x;
}

constexpr Pass_t build_pass(const uint32_t* Mc) {
    Pass_t P{};
    uint32_t rows[12]{};
    rows[0] = 4u;                              // row0 = pack functional (k bit 2)
    int nr = 1;
    uint32_t full[12]{}; int nf = 0; full[nf++] = 4u;
    uint32_t We[4]{};  int nw = 0;
    uint32_t Re[5]{};  int nre = 0;
    {   // row0's read projection over span Mc[3..7]
        uint32_t p0 = 0;
        for (int j = 0; j < 5; j++)
            p0 |= (uint32_t)(__builtin_popcount(4u & Mc[3 + j]) & 1) << j;
        uint32_t r = ech_reduce(Re, nre, p0);
        if (r) Re[nre++] = r;
    }
    for (int slot = 0; slot < 4; slot++) {
        uint32_t chosen = 0;
        for (int relax = 0; relax < 3 && !chosen; relax++) {
            for (uint32_t m = 1; m < 4096u && !chosen; m++) {
                if (m & 4u) continue;
                uint32_t wp = (m >> 3) & 15u;          // write lane span, k bits 3..6
                uint32_t wr = ech_reduce(We, nw, wp);
                if (relax < 2 && !wr) continue;
                uint32_t rp = 0;
                for (int j = 0; j < 5; j++)            // read lane span, k bits 3..7
                    rp |= (uint32_t)(__builtin_popcount(m & Mc[3 + j]) & 1) << j;
                uint32_t rr = ech_reduce(Re, nre, rp);
                if (relax < 1 && !rr) continue;
                uint32_t fr = ech_reduce(full, nf, m);
                if (!fr) continue;
                chosen = m; full[nf++] = fr;
                if (wr && nw < 4) We[nw++] = wr;
                if (rr && nre < 5) Re[nre++] = rr;
            }
        }
        rows[nr++] = chosen;
    }
    for (int slot = nr; slot < 12; slot++) {
        for (uint32_t m = 1; m < 4096u; m++) {
            if (m & 4u) continue;
            uint32_t fr = ech_reduce(full, nf, m);
            if (fr) { rows[slot] = m; full[nf++] = fr; break; }
        }
    }
    uint32_t col[12]{}, lmc[12]{};
    for (int j = 0; j < 12; j++) {
        uint32_t c = 0;
        for (int i = 0; i < 12; i++) c |= (uint32_t)((rows[i] >> j) & 1u) << i;
        col[j] = c;
    }
    for (int j = 0; j < 12; j++) {
        uint32_t a = 0, mc = Mc[j];
        for (int q = 0; q < 12; q++) if ((mc >> q) & 1u) a ^= col[q];
        lmc[j] = a;
    }
    for (int j = 0; j < 9; j++) { P.WT[j] = col[3 + j]; P.RT[j] = lmc[3 + j]; }
    for (int j = 0; j < 4; j++) {
        uint32_t a = 0;
        for (int q = 0; q < 2; q++) if ((j >> q) & 1) a ^= col[q];
        P.WL[j] = a;
    }
    for (int l = 0; l < 8; l++) {
        uint32_t a = 0;
        for (int q = 0; q < 3; q++) if ((l >> q) & 1) a ^= lmc[q];
        P.RL[l] = a;
    }
    return P;
}

constexpr Pass9_t build_pass9(const uint32_t* Mc) {
    Pass9_t P{};
    uint32_t rows[9]{};
    rows[0] = 4u;
    int nr = 1;
    uint32_t full[9]{}; int nf = 0; full[nf++] = 4u;
    uint32_t We[4]{};  int nw = 0;
    uint32_t Re[5]{};  int nre = 0;
    {
        uint32_t p0 = 0;
        for (int j = 0; j < 5; j++)
            p0 |= (uint32_t)(__builtin_popcount(4u & Mc[3 + j]) & 1) << j;
        uint32_t r = ech_reduce(Re, nre, p0);
        if (r) Re[nre++] = r;
    }
    for (int slot = 0; slot < 4; slot++) {
        uint32_t chosen = 0;
        for (int relax = 0; relax < 3 && !chosen; relax++) {
            for (uint32_t m = 1; m < 512u && !chosen; m++) {
                if (m & 4u) continue;
                uint32_t wp = (m >> 3) & 15u;
                uint32_t wr = ech_reduce(We, nw, wp);
                if (relax < 2 && !wr) continue;
                uint32_t rp = 0;
                for (int j = 0; j < 5; j++)
                    rp |= (uint32_t)(__builtin_popcount(m & Mc[3 + j]) & 1) << j;
                uint32_t rr = ech_reduce(Re, nre, rp);
                if (relax < 1 && !rr) continue;
                uint32_t fr = ech_reduce(full, nf, m);
                if (!fr) continue;
                chosen = m; full[nf++] = fr;
                if (wr && nw < 4) We[nw++] = wr;
                if (rr && nre < 5) Re[nre++] = rr;
            }
        }
        rows[nr++] = chosen;
    }
    for (int slot = nr; slot < 9; slot++) {
        for (uint32_t m = 1; m < 512u; m++) {
            if (m & 4u) continue;
            uint32_t fr = ech_reduce(full, nf, m);
            if (fr) { rows[slot] = m; full[nf++] = fr; break; }
        }
    }
    uint32_t col[9]{}, lmc[9]{};
    for (int j = 0; j < 9; j++) {
        uint32_t c = 0;
        for (int i = 0; i < 9; i++) c |= (uint32_t)((rows[i] >> j) & 1u) << i;
        col[j] = c;
    }
    for (int j = 0; j < 9; j++) {
        uint32_t a = 0, mc = Mc[j];
        for (int q = 0; q < 9; q++) if ((mc >> q) & 1u) a ^= col[q];
        lmc[j] = a;
    }
    for (int j = 0; j < 6; j++) { P.WT[j] = col[3 + j]; P.RT[j] = lmc[3 + j]; }
    for (int j = 0; j < 4; j++) {
        uint32_t a = 0;
        for (int q = 0; q < 2; q++) if ((j >> q) & 1) a ^= col[q];
        P.WL[j] = a;
    }
    for (int l = 0; l < 8; l++) {
        uint32_t a = 0;
        for (int q = 0; q < 3; q++) if ((l >> q) & 1) a ^= lmc[q];
        P.RL[l] = a;
    }
    return P;
}

constexpr CK_t build_ck() {
    CK_t ck{};
    uint32_t Acols[NLAYERS][NQ]{}, Aicol5[NQ]{};
    for (int l = 0; l < NLAYERS; l++) {
        int r = l % (NQ - 1) + 1;
        for (int q = 0; q < NQ; q++) {
            uint32_t v = 1u << q;
            for (int w = NQ - 1; w >= 0; w--) {            // A = T0∘T1∘...∘T11
                int pc = NQ - 1 - w, pt = NQ - 1 - ((w + r) % NQ);
                v ^= ((v >> pc) & 1u) << pt;
            }
            Acols[l][q] = v;
            if (l == NLAYERS - 1) {
                uint32_t u = 1u << q;
                for (int w = 0; w < NQ; w++) {             // A^-1
                    int pc = NQ - 1 - w, pt = NQ - 1 - ((w + r) % NQ);
                    u ^= ((u >> pc) & 1u) << pt;
                }
                Aicol5[q] = u;
            }
        }
    }
    uint32_t Mc9[9]{};
    for (int j = 0; j < 9; j++) Mc9[j] = S1f(1u << j);        // M1
    ck.PA1 = build_pass9(Mc9);
    for (int j = 0; j < 9; j++) Mc9[j] = S2f(1u << j);        // M2
    ck.PA2 = build_pass9(Mc9);
    uint32_t Mc[12]{};
    for (int j = 0; j < 12; j++) Mc[j] = S3f(1u << j);        // M3
    ck.PB = build_pass(Mc);
    for (int l = 1; l < NLAYERS; l++) {                       // M_c = S3.S2.S1.A
        for (int j = 0; j < 12; j++) Mc[j] = S3f(S2f(S1f(Acols[l - 1][j])));
        ck.P1[l] = build_pass(Mc);
    }
    // epilogue: i(k) = A5^-1(Phi(k)), Phi = S1.S2.S3  (col: S1f(S2f(S3f(e_j))))
    uint32_t Mcol[NQ]{};
    for (int j = 0; j < NQ; j++) {
        uint32_t pj = S1f(S2f(S3f(1u << j)));
        uint32_t M = 0;
        for (int m = 0; m < NQ; m++) if ((pj >> m) & 1u) M ^= Aicol5[m];
        Mcol[j] = M;
    }
    for (int p = 0; p < NQ; p++) {
        uint32_t s = 0;
        for (int j = 0; j < NQ; j++) s |= ((Mcol[j] >> p) & 1u) << j;
        ck.frow[p] = s;
    }
    return ck;
}
constexpr CK_t CK = build_ck();

// rotation at local bit Q; m = (m00r,m00i,m01r,m01i); element-wise pk math.
template<int Q>
__device__ __forceinline__ void gate_q(v2f (&PRE)[4], v2f (&PIM)[4], float4 m) {
    v2f bx = {m.x, m.x}, by = {m.y, m.y}, bz = {m.z, m.z}, bw = {m.w, m.w};
    #pragma unroll
    for (int j = 0; j < 4; j++) {
        if (j & (1 << Q)) continue;
        int j2 = j | (1 << Q);
        v2f re0 = PRE[j], im0 = PIM[j], re1 = PRE[j2], im1 = PIM[j2];
        PRE[j]  = __builtin_elementwise_fma(bx, re0,
                  __builtin_elementwise_fma(by, -im0,
                  __builtin_elementwise_fma(bz, re1, -bw * im1)));
        PIM[j]  = __builtin_elementwise_fma(bx, im0,
                  __builtin_elementwise_fma(by, re0,
                  __builtin_elementwise_fma(bz, im1, bw * re1)));
        PRE[j2] = __builtin_elementwise_fma(bx, re1,
                  __builtin_elementwise_fma(by, im1,
                  __builtin_elementwise_fma(bz, -re0, -bw * im0)));
        PIM[j2] = __builtin_elementwise_fma(bx, im1,
                  __builtin_elementwise_fma(by, -re1,
                  __builtin_elementwise_fma(bz, -im0, bw * re0)));
    }
}

// gate on the pack bit (halves .x/.y of each v2f), sign-vector pk math.
__device__ __forceinline__ void pack_gate(v2f (&PRE)[4], v2f (&PIM)[4], float4 m) {
    v2f d1 = {-m.y, m.y}, d2 = {m.z, -m.z};
    #pragma unroll
    for (int j = 0; j < 4; j++) {
        v2f RE = PRE[j], IM = PIM[j];
        v2f sR = {RE.y, RE.x}, sI = {IM.y, IM.x};
        PRE[j] = m.x * RE + d1 * IM + d2 * sR - m.w * sI;
        PIM[j] = m.x * IM - d1 * RE + d2 * sI + m.w * sR;
    }
}

// wave-local pass: b64 writes, lgkmcnt drain, b32 scatter reads.
// Prior reads of this wave's quadrant are already drained: all read values
// feed the preceding gates (in-order DS retire + register dataflow).
template<int IDX>
__device__ __forceinline__ void wl_pass(v2f (&PRE)[4], v2f (&PIM)[4],
                                        float* buf, uint32_t wb, uint32_t rb) {
    constexpr Pass9_t P = (IDX == 0) ? CK.PA1 : CK.PA2;
    v2f* bre = (v2f*)buf;
    v2f* bim = (v2f*)(buf + DIM);
    __asm__ volatile("s_waitcnt lgkmcnt(0)" ::: "memory");
    #pragma unroll
    for (int j = 0; j < 4; j++) {
        uint32_t s = (wb ^ P.WL[j]) >> 1;
        bre[s] = PRE[j]; bim[s] = PIM[j];
    }
    __asm__ volatile("s_waitcnt lgkmcnt(0)" ::: "memory");
    #pragma unroll
    for (int j = 0; j < 4; j++) {
        uint32_t s0 = rb ^ P.RL[j], s1 = rb ^ P.RL[j | 4];
        v2f re, im;
        re.x = buf[s0];       re.y = buf[s1];
        im.x = buf[DIM + s0]; im.y = buf[DIM + s1];
        PRE[j] = re; PIM[j] = im;
    }
}

// cross-wave P3: pre-barrier (drain P2 reads block-wide), write, barrier, read
__device__ __forceinline__ void p3_pass(v2f (&PRE)[4], v2f (&PIM)[4],
                                        float* buf, uint32_t wb, uint32_t rb) {
    constexpr Pass_t P = CK.PB;
    v2f* bre = (v2f*)buf;
    v2f* bim = (v2f*)(buf + DIM);
    __syncthreads();
    #pragma unroll
    for (int j = 0; j < 4; j++) {
        uint32_t s = (wb ^ P.WL[j]) >> 1;
        bre[s] = PRE[j]; bim[s] = PIM[j];
    }
    __syncthreads();
    #pragma unroll
    for (int j = 0; j < 4; j++) {
        uint32_t s0 = rb ^ P.RL[j], s1 = rb ^ P.RL[j | 4];
        v2f re, im;
        re.x = buf[s0];       re.y = buf[s1];
        im.x = buf[DIM + s0]; im.y = buf[DIM + s1];
        PRE[j] = re; PIM[j] = im;
    }
}

// cross-wave rebase P_c, runtime layer index
__device__ __forceinline__ void rebase_pass(v2f (&PRE)[4], v2f (&PIM)[4],
                                            float* buf, int tid, int l) {
    const Pass_t& P = CK.P1[l];
    uint32_t wb = 0, rb = 0;
    #pragma unroll
    for (int j = 0; j < 9; j++) {
        uint32_t sel = (uint32_t)(-(int)((tid >> j) & 1));
        wb ^= sel & P.WT[j];
        rb ^= sel & P.RT[j];
    }
    v2f* bre = (v2f*)buf;
    v2f* bim = (v2f*)(buf + DIM);
    #pragma unroll
    for (int j = 0; j < 4; j++) {
        uint32_t s = (wb ^ P.WL[j]) >> 1;
        bre[s] = PRE[j]; bim[s] = PIM[j];
    }
    __syncthreads();
    #pragma unroll
    for (int j = 0; j < 4; j++) {
        uint32_t s0 = rb ^ P.RL[j], s1 = rb ^ P.RL[j | 4];
        v2f re, im;
        re.x = buf[s0];       re.y = buf[s1];
        im.x = buf[DIM + s0]; im.y = buf[DIM + s1];
        PRE[j] = re; PIM[j] = im;
    }
}

__global__ __launch_bounds__(TPB, 4) void qsim_kernel(
    const float* __restrict__ x,        // [512,12]
    const float* __restrict__ weights,  // [6,12,3]
    const float* __restrict__ Wp,       // [12]
    const float* __restrict__ bptr,     // [1]
    float* __restrict__ out)            // [512]
{
    __shared__ float  lds[2 * 2 * DIM]; // bufA [0,8192): P1/P2/P3; bufB: rebase
    __shared__ float4 smat[NLAYERS * NQ];
    __shared__ float  scs[NQ], sss[NQ];
    __shared__ float  red[8];

    const int tid = threadIdx.x;
    const int b   = blockIdx.x;

    if (tid < NQ) {
        float s_, c_;
        sincosf(0.5f * x[b * NQ + tid], &s_, &c_);
        scs[tid] = c_; sss[tid] = s_;
    }
    if (tid < NLAYERS * NQ) {
        float phi   = weights[tid * 3 + 0];
        float theta = weights[tid * 3 + 1];
        float omega = weights[tid * 3 + 2];
        float st, ct; sincosf(0.5f * theta, &st, &ct);
        float sp, cp; sincosf(0.5f * (phi + omega), &sp, &cp);
        float sm, cm; sincosf(0.5f * (phi - omega), &sm, &cm);
        smat[tid] = make_float4(cp * ct, -sp * ct, -cm * st, -sm * st);
    }
    __syncthreads();

    // init, identity basis: k = (tid<<3)|(h<<2)|j; local bits 0-1 <-> wires
    // 11,10; pack bit 2 <-> wire 9; tid bit t <-> wire 8-t.
    float base = 1.0f;
    #pragma unroll
    for (int t = 0; t < 9; t++) {
        int w = 8 - t;
        base *= ((tid >> t) & 1) ? sss[w] : scs[w];
    }
    v2f PRE[4], PIM[4];
    float c9 = scs[9], s9 = sss[9];
    #pragma unroll
    for (int j = 0; j < 4; j++) {
        float a = base;
        #pragma unroll
        for (int p = 0; p < 2; p++) {
            int w = NQ - 1 - p;
            a *= ((j >> p) & 1) ? sss[w] : scs[w];
        }
        PRE[j].x = a * c9;  PRE[j].y = a * s9;
        PIM[j].x = 0.0f;    PIM[j].y = 0.0f;
    }

    // fixed-pass address bases
    uint32_t p1wb = 0, p1rb = 0, p2wb = 0, p2rb = 0, p3wb = 0, p3rb = 0;
    #pragma unroll
    for (int j = 0; j < 6; j++) {
        uint32_t sel = (uint32_t)(-(int)((tid >> j) & 1));
        p1wb ^= sel & CK.PA1.WT[j]; p1rb ^= sel & CK.PA1.RT[j];
        p2wb ^= sel & CK.PA2.WT[j]; p2rb ^= sel & CK.PA2.RT[j];
    }
    #pragma unroll
    for (int j = 0; j < 9; j++) {
        uint32_t sel = (uint32_t)(-(int)((tid >> j) & 1));
        p3wb ^= sel & CK.PB.WT[j]; p3rb ^= sel & CK.PB.RT[j];
    }
    {
        uint32_t wvb = (uint32_t)(tid & 0x1C0) << 3;   // wave id -> slot bits 9-11
        p1wb |= wvb; p1rb |= wvb; p2wb |= wvb; p2rb |= wvb;
    }

    float* bufA = lds;
    float* bufB = lds + 2 * DIM;

    #pragma clang loop unroll(disable)
    for (int l = 0; l < NLAYERS; l++) {
        if (l > 0) rebase_pass(PRE, PIM, bufB, tid, l);
        const int sb = l * NQ;
        gate_q<0>(PRE, PIM, smat[sb + 11]);
        gate_q<1>(PRE, PIM, smat[sb + 10]);
        pack_gate(PRE, PIM, smat[sb + 9]);
        wl_pass<0>(PRE, PIM, bufA, p1wb, p1rb);
        gate_q<0>(PRE, PIM, smat[sb + 8]);
        gate_q<1>(PRE, PIM, smat[sb + 7]);
        pack_gate(PRE, PIM, smat[sb + 6]);
        wl_pass<1>(PRE, PIM, bufA, p2wb, p2rb);
        gate_q<0>(PRE, PIM, smat[sb + 5]);
        gate_q<1>(PRE, PIM, smat[sb + 4]);
        pack_gate(PRE, PIM, smat[sb + 3]);
        p3_pass(PRE, PIM, bufA, p3wb, p3rb);
        gate_q<0>(PRE, PIM, smat[sb + 2]);
        gate_q<1>(PRE, PIM, smat[sb + 1]);
        pack_gate(PRE, PIM, smat[sb + 0]);
    }

    // expectation: coef = b + sum_p W[11-p]*(1-2*bit_p(i(k))), packed halves
    const float bv = bptr[0];
    float wbT[NQ];
    #pragma unroll
    for (int p = 0; p < NQ; p++) {
        uint32_t row = CK.frow[p];
        int tp = __popc(tid & (int)(row >> 3)) & 1;
        float Wv = Wp[NQ - 1 - p];
        wbT[p] = tp ? -Wv : Wv;
    }
    v2f acc2 = {0.0f, 0.0f};
    #pragma unroll
    for (int j = 0; j < 4; j++) {
        float cx = bv, cy = bv;
        #pragma unroll
        for (int p = 0; p < NQ; p++) {
            uint32_t row = CK.frow[p];
            float s = (__popc(j & (int)(row & 3u)) & 1) ? -wbT[p] : wbT[p];
            cx += s;
            cy += (row & 4u) ? -s : s;
        }
        v2f c = {cx, cy};
        acc2 += (PRE[j] * PRE[j] + PIM[j] * PIM[j]) * c;
    }
    float acc = acc2.x + acc2.y;
    #pragma unroll
    for (int off = 32; off > 0; off >>= 1)
        acc += __shfl_down(acc, off, 64);
    if ((tid & 63) == 0) red[tid >> 6] = acc;
    __syncthreads();
    if (tid == 0) {
        float r = 0.0f;
        #pragma unroll
        for (int wv = 0; wv < 8; wv++) r += red[wv];
        out[b] = r;
    }
}

extern "C" void kernel_launch(void* const* d_in, const int* in_sizes, int n_in,
                              void* d_out, int out_size, void* d_ws, size_t ws_size,
                              hipStream_t stream) {
    const float* x       = (const float*)d_in[0];
    const float* weights = (const float*)d_in[1];
    const float* W       = (const float*)d_in[2];
    const float* bptr    = (const float*)d_in[3];
    qsim_kernel<<<512, TPB, 0, stream>>>(x, weights, W, bptr, (float*)d_out);
}